// Round 3
// baseline (382.996 us; speedup 1.0000x reference)
//
#include <hip/hip_runtime.h>
#include <hip/hip_bf16.h>

#define NLAB  24
#define LDIM  256
#define LSEQ  512
#define DDIM  1024
#define NOUT  12288            /* NLAB*LDIM*2 */
#define NEGV  (-10000.0f)
#define MOFF  50331648L        /* 192*512*512 */

typedef __attribute__((ext_vector_type(8))) short short8;
typedef __attribute__((ext_vector_type(4))) float f32x4;
typedef unsigned short u16;
typedef unsigned int   u32;

typedef const __attribute__((address_space(1))) void gvoid_t;
typedef __attribute__((address_space(3))) void lvoid_t;

__device__ __forceinline__ u16 f2bf(float f) {
  u32 u = __builtin_bit_cast(u32, f);
  u32 r = u + 0x7FFFu + ((u >> 16) & 1u);
  return (u16)(r >> 16);
}

__device__ __forceinline__ void g2l16(const u16* g, u16* l) {
  __builtin_amdgcn_global_load_lds((gvoid_t*)g, (lvoid_t*)l, 16, 0, 0);
}

/* ---------------- fp32 -> bf16 conversion of features and w_ff ------------- */
__global__ void cvt_bf16_kernel(const float* __restrict__ feat,
                                const float* __restrict__ wff,
                                u16* __restrict__ fA, u16* __restrict__ fB) {
  const long NA = 4194304L;      /* 4096*1024 */
  const long NB = 12582912L;     /* 12288*1024 */
  const long NQ = (NA + NB) / 4;
  long stride = (long)gridDim.x * blockDim.x;
  for (long i = (long)blockIdx.x * blockDim.x + threadIdx.x; i < NQ; i += stride) {
    long e = i * 4;
    const float* s; u16* d;
    if (e < NA) { s = feat + e;        d = fA + e; }
    else        { s = wff + (e - NA);  d = fB + (e - NA); }
    float4 v = *reinterpret_cast<const float4*>(s);
    ushort4 o;
    o.x = f2bf(v.x); o.y = f2bf(v.y); o.z = f2bf(v.z); o.w = f2bf(v.w);
    *reinterpret_cast<ushort4*>(d) = o;
  }
}

/* Stage one 256x64 bf16 K-tile into LDS (linear dest, inverse-swizzled src).
   PERM: epilogue column permutation applied to the global row index (B of ff). */
template<int LDK, bool PERM>
__device__ __forceinline__ void stage_tile(const u16* __restrict__ gbase, int row0,
                                           int k0, u16* lbuf, int t) {
#pragma unroll
  for (int l = 0; l < 4; ++l) {
    const int rt = l * 64 + (t >> 3);
    const int ce = ((t & 7) ^ (rt & 7)) << 3;
    int gr = rt;
    if (PERM) gr = (rt & ~31) | ((rt & 15) << 1) | ((rt >> 4) & 1);
    g2l16(gbase + (long)(row0 + gr) * LDK + k0 + ce, lbuf + (l * 512 + t) * 8);
  }
}

#define FRAG_OFF(r, ks, hi) (((r) * 64 + (ks) * 32 + (hi) * 8) ^ (((r) & 7) << 3))

/* ============ FF GEMM, 8-phase counted-vmcnt schedule (T3+T4+T5) =========== */
/* phases per iter (tiles e=2t [ph1-4, slot0], o=2t+1 [ph5-8, slot1]):
   ph1: rd(s0,ks0)+stage A(o)h1 | ph2: stage B(o)h0 | ph3: rd(s0,ks1)+B(o)h1
   ph4: stage A(e+2)h0, vmcnt(2) | ph5: rd(s1,ks0)+A(e+2)h1 | ph6: B(e+2)h0
   ph7: rd(s1,ks1)+B(e+2)h1 | ph8: stage A(o+2)h0, vmcnt(2)
   Every staged half: >=1 barrier after its last reader; landed-by deadlines
   guaranteed by the two counted waits. Tail iter: no stage ph4-8, vmcnt(0)@ph4. */

#define SA_(P,H,KT) do { _Pragma("unroll") for (int l = 2*(H); l < 2*(H)+2; ++l) \
    g2l16(gA[l] + (KT) * 64, &lds[P][0][ldst[l]]); } while (0)
#define SBW(P,H,KT) do { _Pragma("unroll") for (int l = 2*(H); l < 2*(H)+2; ++l) \
    g2l16(gB[l] + (KT) * 64, &lds[P][1][ldst[l]]); } while (0)
#define RD_(P,KS) do { \
    _Pragma("unroll") for (int i = 0; i < 8; ++i) { const int r = wm * 128 + i * 16 + lr; \
      af[i] = *reinterpret_cast<const short8*>(&lds[P][0][FRAG_OFF(r, KS, hi)]); } \
    _Pragma("unroll") for (int j = 0; j < 4; ++j) { const int r = wn * 64 + j * 16 + lr; \
      bfr[j] = *reinterpret_cast<const short8*>(&lds[P][1][FRAG_OFF(r, KS, hi)]); } \
  } while (0)
#define MQ_(AFP,IB) do { \
    _Pragma("unroll") for (int ii = 0; ii < 4; ++ii) \
      _Pragma("unroll") for (int j = 0; j < 4; ++j) \
        acc[(IB)+ii][j] = __builtin_amdgcn_mfma_f32_16x16x32_bf16((AFP)[ii], bfr[j], acc[(IB)+ii][j], 0, 0, 0); \
  } while (0)
#define SB0_() __builtin_amdgcn_sched_barrier(0)
#define BARR_() __builtin_amdgcn_s_barrier()
#define LGKM0_() asm volatile("s_waitcnt lgkmcnt(0)" ::: "memory")
#define VM2_() asm volatile("s_waitcnt vmcnt(2)" ::: "memory")
#define VM0_() asm volatile("s_waitcnt vmcnt(0)" ::: "memory")
#define PH_MFMA(AFP,IB) do { \
    SB0_(); BARR_(); LGKM0_(); SB0_(); \
    __builtin_amdgcn_s_setprio(1); MQ_(AFP, IB); __builtin_amdgcn_s_setprio(0); \
    SB0_(); BARR_(); \
  } while (0)

__global__ __launch_bounds__(512, 2)
void ff_gemm256(const u16* __restrict__ A, const u16* __restrict__ B,
                const float* __restrict__ bff,
                u16* __restrict__ sf, u16* __restrict__ ef) {
  __shared__ __align__(16) u16 lds[2][2][16384];    /* 128 KiB, 2 tile slots */
  const int tid = threadIdx.x, lane = tid & 63, wv = tid >> 6;
  const int wm = wv >> 2, wn = wv & 3;
  const int lr = lane & 15, hi = lane >> 4;

  const int bid = blockIdx.x;
  const int wg  = (bid & 7) * 96 + (bid >> 3);      /* XCD-chunked, bijective */
  const int tm  = wg & 15, tn = wg >> 4;            /* 16 x 48 tiles */
  const int rowA0 = tm * 256, rowB0 = tn * 256;

  /* precomputed per-thread staging addresses (global pre-swizzled, LDS linear) */
  const u16* gA[4]; const u16* gB[4]; int ldst[4];
#pragma unroll
  for (int l = 0; l < 4; ++l) {
    const int rt = l * 64 + (tid >> 3);
    const int ce = ((tid & 7) ^ (rt & 7)) << 3;
    gA[l] = A + (long)(rowA0 + rt) * DDIM + ce;
    const int gr = (rt & ~31) | ((rt & 15) << 1) | ((rt >> 4) & 1);
    gB[l] = B + (long)(rowB0 + gr) * DDIM + ce;
    ldst[l] = (l * 512 + tid) * 8;
  }

  f32x4 acc[8][4] = {};
  short8 af[8], bfr[4];

  /* prologue: tile0 (4 halves) + A(1)h0; wait all but A(1)h0 */
  SA_(0, 0, 0); SA_(0, 1, 0); SBW(0, 0, 0); SBW(0, 1, 0);
  SA_(1, 0, 1);
  SB0_(); VM2_(); BARR_();

#pragma unroll 1
  for (int t = 0; t < 8; ++t) {
    const int o = 2 * t + 1, e2 = 2 * t + 2, o2 = 2 * t + 3;
    const bool more = (t < 7);
    /* ph1 */  RD_(0, 0); SA_(1, 1, o);                 PH_MFMA(af, 0);
    /* ph2 */  SBW(1, 0, o);                            PH_MFMA(af + 4, 4);
    /* ph3 */  RD_(0, 1); SBW(1, 1, o);                 PH_MFMA(af, 0);
    /* ph4 */  if (more) { SA_(0, 0, e2); SB0_(); VM2_(); } else { SB0_(); VM0_(); }
                                                        PH_MFMA(af + 4, 4);
    /* ph5 */  RD_(1, 0); if (more) SA_(0, 1, e2);      PH_MFMA(af, 0);
    /* ph6 */  if (more) SBW(0, 0, e2);                 PH_MFMA(af + 4, 4);
    /* ph7 */  RD_(1, 1); if (more) SBW(0, 1, e2);      PH_MFMA(af, 0);
    /* ph8 */  if (more) { SA_(1, 0, o2); SB0_(); VM2_(); }
                                                        PH_MFMA(af + 4, 4);
  }

  /* epilogue: +bias, relu, bf16; permuted cols -> contiguous-d stores */
#pragma unroll
  for (int j = 0; j < 4; ++j) {
    const int cblk = wn * 64 + j * 16;
    const int o = rowB0 + (cblk & ~31) + 2 * lr + ((cblk >> 4) & 1);
    const float bv = bff[o];
    const int label = o >> 9, d = (o >> 1) & 255, se = o & 1;
    u16* dst = se ? ef : sf;
#pragma unroll
    for (int i = 0; i < 8; ++i) {
#pragma unroll
      for (int r = 0; r < 4; ++r) {
        const int m = rowA0 + wm * 128 + i * 16 + hi * 4 + r;
        const int b = m >> 9, ll = m & 511;
        float v = acc[i][j][r] + bv;
        v = v > 0.f ? v : 0.f;
        dst[((long)(b * NLAB + label) * LSEQ + ll) * LDIM + d] = f2bf(v);
      }
    }
  }
}

/* ------------- Biaffine: per (b,label) S = sf * ef^T, dual write ----------- */
__global__ __launch_bounds__(512, 2)
void biaffine256(const u16* __restrict__ sf, const u16* __restrict__ ef,
                 const float* __restrict__ bias, const int* __restrict__ mask,
                 float* __restrict__ out) {
  __shared__ __align__(16) u16 lds[2][2][16384];    /* 128 KiB */
  const int tid = threadIdx.x, lane = tid & 63, wv = tid >> 6;
  const int wm = wv >> 2, wn = wv & 3;
  const int lr = lane & 15, hi = lane >> 4;

  const int bid = blockIdx.x;
  const int wg  = (bid & 7) * 96 + (bid >> 3);      /* 4 tiles of a bl share an XCD */
  const int bl  = wg >> 2, tile = wg & 3;
  const int tm  = tile >> 1, tn = tile & 1;
  const int b = bl / NLAB, label = bl - b * NLAB;
  const u16* Ab = sf + (long)bl * LSEQ * LDIM;
  const u16* Bb = ef + (long)bl * LSEQ * LDIM;
  const int rowA0 = tm * 256, rowB0 = tn * 256;

  f32x4 acc[8][4] = {};

  stage_tile<LDIM, false>(Ab, rowA0, 0, lds[0][0], tid);
  stage_tile<LDIM, false>(Bb, rowB0, 0, lds[0][1], tid);
  __syncthreads();

  int buf = 0;
  for (int t = 0; t < 4; ++t) {
    if (t < 3) {
      stage_tile<LDIM, false>(Ab, rowA0, (t + 1) * 64, lds[buf ^ 1][0], tid);
      stage_tile<LDIM, false>(Bb, rowB0, (t + 1) * 64, lds[buf ^ 1][1], tid);
    }
    const u16* La = lds[buf][0];
    const u16* Lb = lds[buf][1];
#pragma unroll
    for (int ks = 0; ks < 2; ++ks) {
      short8 af[8], bfr[4];
#pragma unroll
      for (int i = 0; i < 8; ++i) {
        const int r = wm * 128 + i * 16 + lr;
        af[i] = *reinterpret_cast<const short8*>(La + FRAG_OFF(r, ks, hi));
      }
#pragma unroll
      for (int j = 0; j < 4; ++j) {
        const int r = wn * 64 + j * 16 + lr;
        bfr[j] = *reinterpret_cast<const short8*>(Lb + FRAG_OFF(r, ks, hi));
      }
      __builtin_amdgcn_s_setprio(1);
#pragma unroll
      for (int i = 0; i < 8; ++i)
#pragma unroll
        for (int j = 0; j < 4; ++j)
          acc[i][j] = __builtin_amdgcn_mfma_f32_16x16x32_bf16(af[i], bfr[j], acc[i][j], 0, 0, 0);
      __builtin_amdgcn_s_setprio(0);
    }
    __syncthreads();
    buf ^= 1;
  }

  const float bv = bias[label];
  const long obase = (long)bl * LSEQ * LSEQ;
#pragma unroll
  for (int i = 0; i < 8; ++i) {
#pragma unroll
    for (int r = 0; r < 4; ++r) {
      const int s = rowA0 + wm * 128 + i * 16 + hi * 4 + r;
      const bool ms = (mask[b * LSEQ + s] != 0);
      const long rbase = obase + (long)s * LSEQ;
#pragma unroll
      for (int j = 0; j < 4; ++j) {
        const int e = rowB0 + wn * 64 + j * 16 + lr;
        float v = acc[i][j][r] + bv;
        u32 bits = __builtin_bit_cast(u32, v);
        if ((bits & 0x7F800000u) == 0x7F800000u) v = NEGV;  /* inf or nan */
        out[rbase + e] = v;
        const bool keep = (s <= e) && ms && (mask[b * LSEQ + e] != 0);
        out[MOFF + rbase + e] = keep ? v : NEGV;
      }
    }
  }
}

extern "C" void kernel_launch(void* const* d_in, const int* in_sizes, int n_in,
                              void* d_out, int out_size, void* d_ws, size_t ws_size,
                              hipStream_t stream) {
  const float* feat = (const float*)d_in[0];
  const int*   mask = (const int*)d_in[1];
  const float* wff  = (const float*)d_in[2];
  const float* bff  = (const float*)d_in[3];
  const float* bias = (const float*)d_in[4];
  float* out = (float*)d_out;

  u16* fA = (u16*)d_ws;                 /*  4,194,304 elems =  8 MiB  */
  u16* fB = fA + 4194304L;              /* 12,582,912 elems = 24 MiB  */
  u16* sf = fB + 12582912L;             /* 25,165,824 elems = 48 MiB  */
  u16* ef = sf + 25165824L;             /* 25,165,824 elems = 48 MiB  */

  cvt_bf16_kernel<<<2048, 256, 0, stream>>>(feat, wff, fA, fB);
  ff_gemm256<<<768, 512, 0, stream>>>(fA, fB, bff, sf, ef);
  biaffine256<<<768, 512, 0, stream>>>(sf, ef, bias, mask, out);
}

// Round 4
// 260.358 us; speedup vs baseline: 1.4710x; 1.4710x over previous
//
#include <hip/hip_runtime.h>
#include <hip/hip_bf16.h>

#define NLAB  24
#define LDIM  256
#define LSEQ  512
#define DDIM  1024
#define NOUT  12288            /* NLAB*LDIM*2 */
#define NEGV  (-10000.0f)
#define MOFF  50331648L        /* 192*512*512 */

typedef __attribute__((ext_vector_type(8))) short short8;
typedef __attribute__((ext_vector_type(4))) float f32x4;
typedef unsigned short u16;
typedef unsigned int   u32;

typedef const __attribute__((address_space(1))) void gvoid_t;
typedef __attribute__((address_space(3))) void lvoid_t;

__device__ __forceinline__ u16 f2bf(float f) {
  u32 u = __builtin_bit_cast(u32, f);
  u32 r = u + 0x7FFFu + ((u >> 16) & 1u);
  return (u16)(r >> 16);
}

__device__ __forceinline__ void g2l16(const u16* g, u16* l) {
  __builtin_amdgcn_global_load_lds((gvoid_t*)g, (lvoid_t*)l, 16, 0, 0);
}

/* ---------------- fp32 -> bf16 conversion of features and w_ff ------------- */
__global__ void cvt_bf16_kernel(const float* __restrict__ feat,
                                const float* __restrict__ wff,
                                u16* __restrict__ fA, u16* __restrict__ fB) {
  const long NA = 4194304L;      /* 4096*1024 */
  const long NB = 12582912L;     /* 12288*1024 */
  const long NQ = (NA + NB) / 4;
  long stride = (long)gridDim.x * blockDim.x;
  for (long i = (long)blockIdx.x * blockDim.x + threadIdx.x; i < NQ; i += stride) {
    long e = i * 4;
    const float* s; u16* d;
    if (e < NA) { s = feat + e;        d = fA + e; }
    else        { s = wff + (e - NA);  d = fB + (e - NA); }
    float4 v = *reinterpret_cast<const float4*>(s);
    ushort4 o;
    o.x = f2bf(v.x); o.y = f2bf(v.y); o.z = f2bf(v.z); o.w = f2bf(v.w);
    *reinterpret_cast<ushort4*>(d) = o;
  }
}

/* ======== FF GEMM: 256^2 tile, BK=32, 3-slot LDS ring, stage-2-ahead ======== */
/* iter t: read slot t%3, stage tile t+2 -> slot (t+2)%3 (dead since iter t-1).
   End-of-iter vmcnt(4): forces landing of tile t+1 only (issued a full iter
   earlier); tile t+2's 4 loads stay in flight across the barrier (T4).       */
__global__ __launch_bounds__(512, 2)
void ff_gemm256(const u16* __restrict__ A, const u16* __restrict__ B,
                const float* __restrict__ bff,
                u16* __restrict__ sf, u16* __restrict__ ef) {
  __shared__ __align__(16) u16 lds[3][2][8192];   /* 3 slots x {A,B} x 256x32 = 96 KiB */
  const int tid = threadIdx.x, lane = tid & 63, wv = tid >> 6;
  const int wm = wv >> 2, wn = wv & 3;
  const int lr = lane & 15, hi = lane >> 4;

  const int bid = blockIdx.x;
  const int wg  = (bid & 7) * 96 + (bid >> 3);    /* XCD-chunked, bijective */
  const int tm  = wg & 15, tn = wg >> 4;          /* 16 x 48 tiles */
  const int rowA0 = tm * 256, rowB0 = tn * 256;

  /* staging map: per matrix 2 loads/thread; load L covers granule g=L*512+tid.
     granule g holds global (row g>>2, col-granule (g&3)^((g>>3)&3)); LDS dest
     is linear g*16B. Inverse of read swizzle below (both-sides involution). */
  const u16* gAa[2]; const u16* gBa[2]; int dsta[2];
#pragma unroll
  for (int L = 0; L < 2; ++L) {
    const int g = L * 512 + tid;
    const int r = g >> 2;
    const int c = (g & 3) ^ ((g >> 3) & 3);
    gAa[L] = A + (long)(rowA0 + r) * DDIM + c * 8;
    const int gr = (r & ~31) | ((r & 15) << 1) | ((r >> 4) & 1);  /* epilogue perm (B) */
    gBa[L] = B + (long)(rowB0 + gr) * DDIM + c * 8;
    dsta[L] = g * 8;
  }

  /* per-lane ds_read offsets (invariant over K): frag (row r, k-granule hi)
     lives at granule 4r + (hi ^ ((r>>1)&3)) -> 2-way bank conflicts max. */
  int offA[8], offB[4];
#pragma unroll
  for (int i = 0; i < 8; ++i) { const int r = wm * 128 + i * 16 + lr; offA[i] = (4 * r + (hi ^ ((r >> 1) & 3))) * 8; }
#pragma unroll
  for (int j = 0; j < 4; ++j) { const int r = wn * 64 + j * 16 + lr; offB[j] = (4 * r + (hi ^ ((r >> 1) & 3))) * 8; }

  f32x4 acc[8][4] = {};

  /* prologue: stage tiles 0 and 1; wait tile0 (vmcnt leaves tile1 in flight) */
#pragma unroll
  for (int L = 0; L < 2; ++L) g2l16(gAa[L],      &lds[0][0][dsta[L]]);
#pragma unroll
  for (int L = 0; L < 2; ++L) g2l16(gBa[L],      &lds[0][1][dsta[L]]);
#pragma unroll
  for (int L = 0; L < 2; ++L) g2l16(gAa[L] + 32, &lds[1][0][dsta[L]]);
#pragma unroll
  for (int L = 0; L < 2; ++L) g2l16(gBa[L] + 32, &lds[1][1][dsta[L]]);
  __builtin_amdgcn_sched_barrier(0);
  asm volatile("s_waitcnt vmcnt(4)" ::: "memory");
  __builtin_amdgcn_s_barrier();

  int slot = 0;
#pragma unroll 1
  for (int t = 0; t < 32; ++t) {
    const u16* La = lds[slot][0];
    const u16* Lb = lds[slot][1];
    short8 af[8], bfr[4];
#pragma unroll
    for (int i = 0; i < 8; ++i) af[i] = *reinterpret_cast<const short8*>(La + offA[i]);
#pragma unroll
    for (int j = 0; j < 4; ++j) bfr[j] = *reinterpret_cast<const short8*>(Lb + offB[j]);
    if (t < 30) {
      int ns = slot + 2; if (ns >= 3) ns -= 3;
      const int ko = (t + 2) * 32;
#pragma unroll
      for (int L = 0; L < 2; ++L) g2l16(gAa[L] + ko, &lds[ns][0][dsta[L]]);
#pragma unroll
      for (int L = 0; L < 2; ++L) g2l16(gBa[L] + ko, &lds[ns][1][dsta[L]]);
    }
    asm volatile("s_waitcnt lgkmcnt(0)" ::: "memory");
    __builtin_amdgcn_sched_barrier(0);
    __builtin_amdgcn_s_setprio(1);
#pragma unroll
    for (int i = 0; i < 8; ++i)
#pragma unroll
      for (int j = 0; j < 4; ++j)
        acc[i][j] = __builtin_amdgcn_mfma_f32_16x16x32_bf16(af[i], bfr[j], acc[i][j], 0, 0, 0);
    __builtin_amdgcn_s_setprio(0);
    __builtin_amdgcn_sched_barrier(0);
    if (t < 30)       asm volatile("s_waitcnt vmcnt(4)" ::: "memory");
    else if (t == 30) asm volatile("s_waitcnt vmcnt(0)" ::: "memory");
    __builtin_amdgcn_s_barrier();
    slot += 1; if (slot >= 3) slot -= 3;
  }

  /* epilogue: +bias, relu, bf16; permuted cols -> contiguous-d stores */
#pragma unroll
  for (int j = 0; j < 4; ++j) {
    const int cblk = wn * 64 + j * 16;
    const int o = rowB0 + (cblk & ~31) + 2 * lr + ((cblk >> 4) & 1);
    const float bv = bff[o];
    const int label = o >> 9, d = (o >> 1) & 255, se = o & 1;
    u16* dst = se ? ef : sf;
#pragma unroll
    for (int i = 0; i < 8; ++i) {
#pragma unroll
      for (int r = 0; r < 4; ++r) {
        const int m = rowA0 + wm * 128 + i * 16 + hi * 4 + r;
        const int b = m >> 9, ll = m & 511;
        float v = acc[i][j][r] + bv;
        v = v > 0.f ? v : 0.f;
        dst[((long)(b * NLAB + label) * LSEQ + ll) * LDIM + d] = f2bf(v);
      }
    }
  }
}

/* ---- Biaffine (unchanged, round-2): per (b,label) S = sf * ef^T, dual write ---- */
template<int LDK, bool PERM>
__device__ __forceinline__ void stage_tile(const u16* __restrict__ gbase, int row0,
                                           int k0, u16* lbuf, int t) {
#pragma unroll
  for (int l = 0; l < 4; ++l) {
    const int rt = l * 64 + (t >> 3);
    const int ce = ((t & 7) ^ (rt & 7)) << 3;
    int gr = rt;
    if (PERM) gr = (rt & ~31) | ((rt & 15) << 1) | ((rt >> 4) & 1);
    g2l16(gbase + (long)(row0 + gr) * LDK + k0 + ce, lbuf + (l * 512 + t) * 8);
  }
}

#define FRAG_OFF(r, ks, hi) (((r) * 64 + (ks) * 32 + (hi) * 8) ^ (((r) & 7) << 3))

__global__ __launch_bounds__(512, 2)
void biaffine256(const u16* __restrict__ sf, const u16* __restrict__ ef,
                 const float* __restrict__ bias, const int* __restrict__ mask,
                 float* __restrict__ out) {
  __shared__ __align__(16) u16 lds[2][2][16384];    /* 128 KiB */
  const int tid = threadIdx.x, lane = tid & 63, wv = tid >> 6;
  const int wm = wv >> 2, wn = wv & 3;
  const int lr = lane & 15, hi = lane >> 4;

  const int bid = blockIdx.x;
  const int wg  = (bid & 7) * 96 + (bid >> 3);      /* 4 tiles of a bl share an XCD */
  const int bl  = wg >> 2, tile = wg & 3;
  const int tm  = tile >> 1, tn = tile & 1;
  const int b = bl / NLAB, label = bl - b * NLAB;
  const u16* Ab = sf + (long)bl * LSEQ * LDIM;
  const u16* Bb = ef + (long)bl * LSEQ * LDIM;
  const int rowA0 = tm * 256, rowB0 = tn * 256;

  f32x4 acc[8][4] = {};

  stage_tile<LDIM, false>(Ab, rowA0, 0, lds[0][0], tid);
  stage_tile<LDIM, false>(Bb, rowB0, 0, lds[0][1], tid);
  __syncthreads();

  int buf = 0;
  for (int t = 0; t < 4; ++t) {
    if (t < 3) {
      stage_tile<LDIM, false>(Ab, rowA0, (t + 1) * 64, lds[buf ^ 1][0], tid);
      stage_tile<LDIM, false>(Bb, rowB0, (t + 1) * 64, lds[buf ^ 1][1], tid);
    }
    const u16* La = lds[buf][0];
    const u16* Lb = lds[buf][1];
#pragma unroll
    for (int ks = 0; ks < 2; ++ks) {
      short8 af[8], bfr[4];
#pragma unroll
      for (int i = 0; i < 8; ++i) {
        const int r = wm * 128 + i * 16 + lr;
        af[i] = *reinterpret_cast<const short8*>(La + FRAG_OFF(r, ks, hi));
      }
#pragma unroll
      for (int j = 0; j < 4; ++j) {
        const int r = wn * 64 + j * 16 + lr;
        bfr[j] = *reinterpret_cast<const short8*>(Lb + FRAG_OFF(r, ks, hi));
      }
      __builtin_amdgcn_s_setprio(1);
#pragma unroll
      for (int i = 0; i < 8; ++i)
#pragma unroll
        for (int j = 0; j < 4; ++j)
          acc[i][j] = __builtin_amdgcn_mfma_f32_16x16x32_bf16(af[i], bfr[j], acc[i][j], 0, 0, 0);
      __builtin_amdgcn_s_setprio(0);
    }
    __syncthreads();
    buf ^= 1;
  }

  const float bv = bias[label];
  const long obase = (long)bl * LSEQ * LSEQ;
#pragma unroll
  for (int i = 0; i < 8; ++i) {
#pragma unroll
    for (int r = 0; r < 4; ++r) {
      const int s = rowA0 + wm * 128 + i * 16 + hi * 4 + r;
      const bool ms = (mask[b * LSEQ + s] != 0);
      const long rbase = obase + (long)s * LSEQ;
#pragma unroll
      for (int j = 0; j < 4; ++j) {
        const int e = rowB0 + wn * 64 + j * 16 + lr;
        float v = acc[i][j][r] + bv;
        u32 bits = __builtin_bit_cast(u32, v);
        if ((bits & 0x7F800000u) == 0x7F800000u) v = NEGV;  /* inf or nan */
        out[rbase + e] = v;
        const bool keep = (s <= e) && ms && (mask[b * LSEQ + e] != 0);
        out[MOFF + rbase + e] = keep ? v : NEGV;
      }
    }
  }
}

extern "C" void kernel_launch(void* const* d_in, const int* in_sizes, int n_in,
                              void* d_out, int out_size, void* d_ws, size_t ws_size,
                              hipStream_t stream) {
  const float* feat = (const float*)d_in[0];
  const int*   mask = (const int*)d_in[1];
  const float* wff  = (const float*)d_in[2];
  const float* bff  = (const float*)d_in[3];
  const float* bias = (const float*)d_in[4];
  float* out = (float*)d_out;

  u16* fA = (u16*)d_ws;                 /*  4,194,304 elems =  8 MiB  */
  u16* fB = fA + 4194304L;              /* 12,582,912 elems = 24 MiB  */
  u16* sf = fB + 12582912L;             /* 25,165,824 elems = 48 MiB  */
  u16* ef = sf + 25165824L;             /* 25,165,824 elems = 48 MiB  */

  cvt_bf16_kernel<<<2048, 256, 0, stream>>>(feat, wff, fA, fB);
  ff_gemm256<<<768, 512, 0, stream>>>(fA, fB, bff, sf, ef);
  biaffine256<<<768, 512, 0, stream>>>(sf, ef, bias, mask, out);
}